// Round 3
// baseline (107.535 us; speedup 1.0000x reference)
//
#include <hip/hip_runtime.h>
#include <math.h>

#define NQ     4
#define IMGD   28
#define HP     14          // patches per spatial dim
#define NPATCH 196         // 14*14
#define FEAT   784         // 196*4
#define HID    20
#define NCLS   2

// CRZ ring composed phase integer k(b) = sum_i b_i*(2*b_{(i+1)%4}-1),
// idx = b0*8 + b1*4 + b2*2 + b3 (wire0 = MSB per reference axis order).
// Hand-verified per index against the formula (twice).
__device__ __constant__ int d_ktab[16] = {0,-1,-1,0,-1,-2,0,1,-1,0,-2,1,0,1,1,4};

__global__ __launch_bounds__(256) void fused_qnn_kernel(
    const float* __restrict__ x,         // [2048,1,28,28]
    const float* __restrict__ ry_theta,  // [1]
    const float* __restrict__ crz_theta, // [1]
    const float* __restrict__ fc1_w,     // [20,784]
    const float* __restrict__ fc1_b,     // [20]
    const float* __restrict__ fc2_w,     // [2,20]
    const float* __restrict__ fc2_b,     // [2]
    float* __restrict__ out)             // [2048,2]
{
    __shared__ float zs[FEAT];
    __shared__ float pc_s[16], ps_s[16]; // CRZ phase tables (block-uniform)
    __shared__ float rycs[2];            // RY cos/sin (block-uniform)
    __shared__ float hid_s[HID];

    const int tid = threadIdx.x;
    const int b   = blockIdx.x;

    // Parallel block-uniform setup: 16 lanes -> CRZ table, lane 16 -> RY pair.
    // (Precise sincosf here: runs once per block, negligible.)
    if (tid < 16) {
        float sv, cv;
        sincosf(0.5f * crz_theta[0] * (float)d_ktab[tid], &sv, &cv);
        pc_s[tid] = cv; ps_s[tid] = sv;
    } else if (tid == 16) {
        float sv, cv;
        sincosf(0.5f * ry_theta[0], &sv, &cv);
        rycs[0] = cv; rycs[1] = sv;
    }
    __syncthreads();

    // ---- Phase 1: one patch per thread (196 active) -> z into LDS ----
    if (tid < NPATCH) {
        const int ph = tid / HP, pw = tid % HP;
        const float* xb = x + (size_t)b * (IMGD * IMGD);
        // 2x2 patch at (2ph, 2pw); rows are 8B-aligned at even columns
        const float2 p0 = *(const float2*)(xb + (2 * ph)     * IMGD + 2 * pw);
        const float2 p1 = *(const float2*)(xb + (2 * ph + 1) * IMGD + 2 * pw);
        const float ang[4] = {p0.x, p0.y, p1.x, p1.y};

        // Native sincos: |ang/2| <~ 3 (N(0,1) inputs), abs err ~1e-6 -> safe.
        float Ac[4], As[4];
        #pragma unroll
        for (int k = 0; k < 4; ++k) __sincosf(0.5f * ang[k], &As[k], &Ac[k]);

        // product state (real)
        float cr[16], ci[16];
        #pragma unroll
        for (int i = 0; i < 16; ++i) {
            cr[i] = ((i & 8) ? As[0] : Ac[0]) * ((i & 4) ? As[1] : Ac[1]) *
                    ((i & 2) ? As[2] : Ac[2]) * ((i & 1) ? As[3] : Ac[3]);
            ci[i] = 0.0f;
        }

        const float c = rycs[0], s = rycs[1];
        #pragma unroll
        for (int layer = 0; layer < 2; ++layer) {
            // CRZ ring: diagonal complex phase per basis state.
            // Layer 0: ci==0 const-propagates (loop fully unrolled) -> DCE'd.
            #pragma unroll
            for (int i = 0; i < 16; ++i) {
                const float pr = pc_s[i], pi = ps_s[i];
                const float nr = cr[i] * pr - ci[i] * pi;
                const float ni = cr[i] * pi + ci[i] * pr;
                cr[i] = nr; ci[i] = ni;
            }
            // RY on each wire (real 2x2 rotation on 8 amplitude pairs)
            #pragma unroll
            for (int w = 0; w < 4; ++w) {
                const int m = 8 >> w;
                #pragma unroll
                for (int i = 0; i < 16; ++i) {
                    if (i & m) continue;
                    const int j = i | m;
                    const float a0r = cr[i], a1r = cr[j];
                    const float a0i = ci[i], a1i = ci[j];
                    cr[i] = c * a0r - s * a1r;
                    cr[j] = s * a0r + c * a1r;
                    ci[i] = c * a0i - s * a1i;
                    ci[j] = s * a0i + c * a1i;
                }
            }
        }

        // PauliZ expectations
        float z0 = 0.f, z1 = 0.f, z2 = 0.f, z3 = 0.f;
        #pragma unroll
        for (int i = 0; i < 16; ++i) {
            const float p = cr[i] * cr[i] + ci[i] * ci[i];
            z0 += (i & 8) ? -p : p;
            z1 += (i & 4) ? -p : p;
            z2 += (i & 2) ? -p : p;
            z3 += (i & 1) ? -p : p;
        }
        *((float4*)&zs[tid * 4]) = make_float4(z0, z1, z2, z3);
    }
    __syncthreads();

    // ---- Phase 2: FC1 (784 -> 20), 4 waves x 5 hidden units ----
    const int wave = tid >> 6;
    const int lane = tid & 63;
    #pragma unroll
    for (int hh = 0; hh < 5; ++hh) {
        const int h = wave * 5 + hh;
        const float* wrow = fc1_w + h * FEAT;
        float acc = 0.f;
        #pragma unroll
        for (int f = lane; f < FEAT; f += 64)   // 13 iters, last partial (784=12*64+16)
            acc += zs[f] * wrow[f];
        #pragma unroll
        for (int off = 32; off > 0; off >>= 1)
            acc += __shfl_down(acc, off, 64);
        if (lane == 0) hid_s[h] = acc + fc1_b[h];
    }
    __syncthreads();

    // ---- Phase 3: ReLU + FC2 (20 -> 2) ----
    if (tid < NCLS) {
        float acc = fc2_b[tid];
        #pragma unroll
        for (int h = 0; h < HID; ++h)
            acc += fmaxf(hid_s[h], 0.f) * fc2_w[tid * HID + h];
        out[b * NCLS + tid] = acc;
    }
}

extern "C" void kernel_launch(void* const* d_in, const int* in_sizes, int n_in,
                              void* d_out, int out_size, void* d_ws, size_t ws_size,
                              hipStream_t stream) {
    const float* x         = (const float*)d_in[0];
    const float* ry_theta  = (const float*)d_in[1];
    const float* crz_theta = (const float*)d_in[2];
    const float* fc1_w     = (const float*)d_in[3];
    const float* fc1_b     = (const float*)d_in[4];
    const float* fc2_w     = (const float*)d_in[5];
    const float* fc2_b     = (const float*)d_in[6];
    float* out = (float*)d_out;

    fused_qnn_kernel<<<2048, 256, 0, stream>>>(
        x, ry_theta, crz_theta, fc1_w, fc1_b, fc2_w, fc2_b, out);
}

// Round 4
// 98.615 us; speedup vs baseline: 1.0905x; 1.0905x over previous
//
#include <hip/hip_runtime.h>
#include <math.h>

#define NQ     4
#define IMGD   28
#define HP     14          // patches per spatial dim
#define NPATCH 196         // 14*14
#define BATCH  2048
#define FEAT   784         // 196*4
#define HID    20
#define NCLS   2

// CRZ ring composed phase integer k(b) = sum_i b_i*(2*b_{(i+1)%4}-1),
// idx = b0*8 + b1*4 + b2*2 + b3 (wire0 = MSB per reference axis order).
__device__ __constant__ int d_ktab[16] = {0,-1,-1,0,-1,-2,0,1,-1,0,-2,1,0,1,1,4};

// ---------------------------------------------------------------------------
// Kernel A: one thread per patch -> z[b, patch*4 .. +3]. No LDS, no barriers.
// CRZ phases built in-register from ONE __sincosf via double-angle identities
// (|k| in {0,1,2,4} only).
// ---------------------------------------------------------------------------
__global__ __launch_bounds__(256) void patch_z_kernel(
    const float* __restrict__ x,         // [2048,1,28,28]
    const float* __restrict__ ry_theta,  // [1]
    const float* __restrict__ crz_theta, // [1]
    float* __restrict__ z)               // [2048,784] in d_ws
{
    const int p  = blockIdx.x * 256 + threadIdx.x;   // 1568*256 == 401408 exact
    const int b  = p / NPATCH;
    const int r  = p - b * NPATCH;
    const int ph = r / HP, pw = r - ph * HP;

    // CRZ phase values for |k| = 1,2,4 from one native sincos + double angle.
    float c1, s1;
    __sincosf(0.5f * crz_theta[0], &s1, &c1);
    const float c2 = c1 * c1 - s1 * s1, s2 = 2.f * c1 * s1;
    const float c4 = c2 * c2 - s2 * s2, s4 = 2.f * c2 * s2;
    // Per-amplitude phase (compile-time selected; k={0,-1,-1,0,-1,-2,0,1,-1,0,-2,1,0,1,1,4})
    const float pc[16] = {1.f,c1,c1,1.f,c1,c2,1.f,c1,c1,1.f,c2,c1,1.f,c1,c1,c4};
    const float ps[16] = {0.f,-s1,-s1,0.f,-s1,-s2,0.f,s1,-s1,0.f,-s2,s1,0.f,s1,s1,s4};

    float c, s;
    __sincosf(0.5f * ry_theta[0], &s, &c);

    const float* xb = x + (size_t)b * (IMGD * IMGD);
    const float2 p0 = *(const float2*)(xb + (2 * ph)     * IMGD + 2 * pw);
    const float2 p1 = *(const float2*)(xb + (2 * ph + 1) * IMGD + 2 * pw);
    const float ang[4] = {p0.x, p0.y, p1.x, p1.y};

    float Ac[4], As[4];
    #pragma unroll
    for (int k = 0; k < 4; ++k) __sincosf(0.5f * ang[k], &As[k], &Ac[k]);

    float cr[16], ci[16];
    #pragma unroll
    for (int i = 0; i < 16; ++i) {
        cr[i] = ((i & 8) ? As[0] : Ac[0]) * ((i & 4) ? As[1] : Ac[1]) *
                ((i & 2) ? As[2] : Ac[2]) * ((i & 1) ? As[3] : Ac[3]);
        ci[i] = 0.0f;
    }

    #pragma unroll
    for (int layer = 0; layer < 2; ++layer) {
        // CRZ ring (diagonal). Layer 0: ci==0 const-propagates -> DCE'd.
        #pragma unroll
        for (int i = 0; i < 16; ++i) {
            const float nr = cr[i] * pc[i] - ci[i] * ps[i];
            const float ni = cr[i] * ps[i] + ci[i] * pc[i];
            cr[i] = nr; ci[i] = ni;
        }
        // RY on each wire (real 2x2 rotation on 8 amplitude pairs)
        #pragma unroll
        for (int w = 0; w < 4; ++w) {
            const int m = 8 >> w;
            #pragma unroll
            for (int i = 0; i < 16; ++i) {
                if (i & m) continue;
                const int j = i | m;
                const float a0r = cr[i], a1r = cr[j];
                const float a0i = ci[i], a1i = ci[j];
                cr[i] = c * a0r - s * a1r;
                cr[j] = s * a0r + c * a1r;
                ci[i] = c * a0i - s * a1i;
                ci[j] = s * a0i + c * a1i;
            }
        }
    }

    float z0 = 0.f, z1 = 0.f, z2 = 0.f, z3 = 0.f;
    #pragma unroll
    for (int i = 0; i < 16; ++i) {
        const float pr = cr[i] * cr[i] + ci[i] * ci[i];
        z0 += (i & 8) ? -pr : pr;
        z1 += (i & 4) ? -pr : pr;
        z2 += (i & 2) ? -pr : pr;
        z3 += (i & 1) ? -pr : pr;
    }
    *((float4*)&z[(size_t)p * 4]) = make_float4(z0, z1, z2, z3);  // coalesced 16B
}

// ---------------------------------------------------------------------------
// Kernel B: one block per image. Stage z row (3136B) in LDS, FC1 via
// 4 waves x 5 hidden units + shuffle reduce, then ReLU+FC2.
// Low VGPR -> high occupancy hides shuffle/L2 latency.
// ---------------------------------------------------------------------------
__global__ __launch_bounds__(256) void fc_kernel(
    const float* __restrict__ z,      // [2048,784] in d_ws
    const float* __restrict__ fc1_w,  // [20,784]
    const float* __restrict__ fc1_b,  // [20]
    const float* __restrict__ fc2_w,  // [2,20]
    const float* __restrict__ fc2_b,  // [2]
    float* __restrict__ out)          // [2048,2]
{
    __shared__ float zs[FEAT];
    __shared__ float hid_s[HID];

    const int tid = threadIdx.x;
    const int b   = blockIdx.x;

    if (tid < NPATCH)  // 196 x float4 = 3136B, coalesced
        ((float4*)zs)[tid] = ((const float4*)(z + (size_t)b * FEAT))[tid];
    __syncthreads();

    const int wave = tid >> 6;
    const int lane = tid & 63;
    #pragma unroll
    for (int hh = 0; hh < 5; ++hh) {
        const int h = wave * 5 + hh;
        const float* wrow = fc1_w + h * FEAT;
        float acc = 0.f;
        #pragma unroll
        for (int f = lane; f < FEAT; f += 64)   // 13 iters, last partial
            acc += zs[f] * wrow[f];
        #pragma unroll
        for (int off = 32; off > 0; off >>= 1)
            acc += __shfl_down(acc, off, 64);
        if (lane == 0) hid_s[h] = acc + fc1_b[h];
    }
    __syncthreads();

    if (tid < NCLS) {
        float acc = fc2_b[tid];
        #pragma unroll
        for (int h = 0; h < HID; ++h)
            acc += fmaxf(hid_s[h], 0.f) * fc2_w[tid * HID + h];
        out[b * NCLS + tid] = acc;
    }
}

// ---------------------------------------------------------------------------
// Fallback: proven fused kernel (round-3 passed), used only if ws too small.
// ---------------------------------------------------------------------------
__global__ __launch_bounds__(256) void fused_qnn_kernel(
    const float* __restrict__ x, const float* __restrict__ ry_theta,
    const float* __restrict__ crz_theta, const float* __restrict__ fc1_w,
    const float* __restrict__ fc1_b, const float* __restrict__ fc2_w,
    const float* __restrict__ fc2_b, float* __restrict__ out)
{
    __shared__ float zs[FEAT];
    __shared__ float pc_s[16], ps_s[16];
    __shared__ float rycs[2];
    __shared__ float hid_s[HID];

    const int tid = threadIdx.x;
    const int b   = blockIdx.x;

    if (tid < 16) {
        float sv, cv;
        sincosf(0.5f * crz_theta[0] * (float)d_ktab[tid], &sv, &cv);
        pc_s[tid] = cv; ps_s[tid] = sv;
    } else if (tid == 16) {
        float sv, cv;
        sincosf(0.5f * ry_theta[0], &sv, &cv);
        rycs[0] = cv; rycs[1] = sv;
    }
    __syncthreads();

    if (tid < NPATCH) {
        const int ph = tid / HP, pw = tid % HP;
        const float* xb = x + (size_t)b * (IMGD * IMGD);
        const float2 p0 = *(const float2*)(xb + (2 * ph)     * IMGD + 2 * pw);
        const float2 p1 = *(const float2*)(xb + (2 * ph + 1) * IMGD + 2 * pw);
        const float ang[4] = {p0.x, p0.y, p1.x, p1.y};

        float Ac[4], As[4];
        #pragma unroll
        for (int k = 0; k < 4; ++k) __sincosf(0.5f * ang[k], &As[k], &Ac[k]);

        float cr[16], ci[16];
        #pragma unroll
        for (int i = 0; i < 16; ++i) {
            cr[i] = ((i & 8) ? As[0] : Ac[0]) * ((i & 4) ? As[1] : Ac[1]) *
                    ((i & 2) ? As[2] : Ac[2]) * ((i & 1) ? As[3] : Ac[3]);
            ci[i] = 0.0f;
        }

        const float c = rycs[0], s = rycs[1];
        #pragma unroll
        for (int layer = 0; layer < 2; ++layer) {
            #pragma unroll
            for (int i = 0; i < 16; ++i) {
                const float pr = pc_s[i], pi = ps_s[i];
                const float nr = cr[i] * pr - ci[i] * pi;
                const float ni = cr[i] * pi + ci[i] * pr;
                cr[i] = nr; ci[i] = ni;
            }
            #pragma unroll
            for (int w = 0; w < 4; ++w) {
                const int m = 8 >> w;
                #pragma unroll
                for (int i = 0; i < 16; ++i) {
                    if (i & m) continue;
                    const int j = i | m;
                    const float a0r = cr[i], a1r = cr[j];
                    const float a0i = ci[i], a1i = ci[j];
                    cr[i] = c * a0r - s * a1r;
                    cr[j] = s * a0r + c * a1r;
                    ci[i] = c * a0i - s * a1i;
                    ci[j] = s * a0i + c * a1i;
                }
            }
        }

        float z0 = 0.f, z1 = 0.f, z2 = 0.f, z3 = 0.f;
        #pragma unroll
        for (int i = 0; i < 16; ++i) {
            const float pr = cr[i] * cr[i] + ci[i] * ci[i];
            z0 += (i & 8) ? -pr : pr;
            z1 += (i & 4) ? -pr : pr;
            z2 += (i & 2) ? -pr : pr;
            z3 += (i & 1) ? -pr : pr;
        }
        *((float4*)&zs[tid * 4]) = make_float4(z0, z1, z2, z3);
    }
    __syncthreads();

    const int wave = tid >> 6;
    const int lane = tid & 63;
    #pragma unroll
    for (int hh = 0; hh < 5; ++hh) {
        const int h = wave * 5 + hh;
        const float* wrow = fc1_w + h * FEAT;
        float acc = 0.f;
        #pragma unroll
        for (int f = lane; f < FEAT; f += 64)
            acc += zs[f] * wrow[f];
        #pragma unroll
        for (int off = 32; off > 0; off >>= 1)
            acc += __shfl_down(acc, off, 64);
        if (lane == 0) hid_s[h] = acc + fc1_b[h];
    }
    __syncthreads();

    if (tid < NCLS) {
        float acc = fc2_b[tid];
        #pragma unroll
        for (int h = 0; h < HID; ++h)
            acc += fmaxf(hid_s[h], 0.f) * fc2_w[tid * HID + h];
        out[b * NCLS + tid] = acc;
    }
}

extern "C" void kernel_launch(void* const* d_in, const int* in_sizes, int n_in,
                              void* d_out, int out_size, void* d_ws, size_t ws_size,
                              hipStream_t stream) {
    const float* x         = (const float*)d_in[0];
    const float* ry_theta  = (const float*)d_in[1];
    const float* crz_theta = (const float*)d_in[2];
    const float* fc1_w     = (const float*)d_in[3];
    const float* fc1_b     = (const float*)d_in[4];
    const float* fc2_w     = (const float*)d_in[5];
    const float* fc2_b     = (const float*)d_in[6];
    float* out = (float*)d_out;

    const size_t z_bytes = (size_t)BATCH * FEAT * sizeof(float);  // 6.42 MB
    if (ws_size >= z_bytes) {
        float* z = (float*)d_ws;
        patch_z_kernel<<<(BATCH * NPATCH) / 256, 256, 0, stream>>>(
            x, ry_theta, crz_theta, z);
        fc_kernel<<<BATCH, 256, 0, stream>>>(z, fc1_w, fc1_b, fc2_w, fc2_b, out);
    } else {
        fused_qnn_kernel<<<BATCH, 256, 0, stream>>>(
            x, ry_theta, crz_theta, fc1_w, fc1_b, fc2_w, fc2_b, out);
    }
}